// Round 5
// baseline (20937.653 us; speedup 1.0000x reference)
//
#include <hip/hip_runtime.h>

typedef __bf16 bf16;
typedef bf16 bf16x2 __attribute__((ext_vector_type(2)));
typedef bf16 bf16x4 __attribute__((ext_vector_type(4)));
typedef bf16 bf16x8 __attribute__((ext_vector_type(8)));
typedef float f32x4 __attribute__((ext_vector_type(4)));

#define DEVFN __device__ __forceinline__

constexpr int cV = 50000, cE = 256, cH = 512, cM = 100, cH2 = 256;
constexpr int cB = 64, cS = 400, cT = 25, cEOS = 2;
constexpr int cSB = cS * cB;          // 25600
constexpr int cG2 = 3 * cH2;          // 768
constexpr int cKcat = 1280;           // [c(512) | wemb(256) | h(512)]
constexpr int cN4 = 2048;             // interleaved r,z,inn,hn rows
constexpr int cNTV = (cV + 63) / 64;  // 782
constexpr int cLB = 196;              // logits blocks in dec_k1

// concatenated bf16 weight cache offsets (elements)
constexpr size_t OFF_WV = 0;
constexpr size_t N_WV = (size_t)cV * cH;
constexpr size_t OFF_WIHF = OFF_WV + N_WV;
constexpr size_t N_WIH = (size_t)cG2 * cE;
constexpr size_t OFF_WHHF = OFF_WIHF + N_WIH;
constexpr size_t N_WHH = (size_t)cG2 * cH2;
constexpr size_t OFF_WIHB = OFF_WHHF + N_WHH;
constexpr size_t OFF_WHHB = OFF_WIHB + N_WIH;
constexpr size_t OFF_W1 = OFF_WHHB + N_WHH;
constexpr size_t N_WSQ = (size_t)cH * cH;
constexpr size_t OFF_W2 = OFF_W1 + N_WSQ;
constexpr size_t OFF_WE = OFF_W2 + N_WSQ;
constexpr size_t N_WE = (size_t)cM * cH;
constexpr size_t TOT_W = OFF_WE + N_WE;

struct GArgs {
  const bf16* A; const bf16* Bw; const float* bias;
  float* outF; bf16* outBf;
  const float* auxF; const bf16* auxBf;
  float* partials;
  int M, N, K, ldo;
};

DEVFN float sigm(float x) { return 1.f / (1.f + __expf(-x)); }
DEVFN float tanh_f(float x) {
  float e2 = __expf(2.f * x);
  return 1.f - 2.f / (e2 + 1.f);
}

// ---------------- generic 64x64-per-wave MFMA GEMM: C = A(MxK) * B(NxK)^T ----------------
// EPI 0: outF = acc + bias ; EPI 1: sgate -> bf16 ; EPI 4: transposed epT[b][n][s]
template <int EPI>
__global__ __launch_bounds__(256) void gemm64_k(GArgs g) {
  const int tid = threadIdx.x;
  const int w = blockIdx.x * 4 + (tid >> 6);
  const int tM = g.M >> 6;
  const int tN = (g.N + 63) >> 6;
  if (w >= tM * tN) return;
  const int im = w % tM, in = w / tM;
  const int m0 = im << 6, n0 = in << 6;
  const int lane = tid & 63, lr = lane & 15, lh = lane >> 4;

  f32x4 acc[4][4];
#pragma unroll
  for (int i = 0; i < 4; ++i)
#pragma unroll
    for (int j = 0; j < 4; ++j)
#pragma unroll
      for (int r = 0; r < 4; ++r) acc[i][j][r] = 0.f;

  bf16x8 bz;
#pragma unroll
  for (int q = 0; q < 8; ++q) bz[q] = (bf16)0.f;

  const int K = g.K;
#pragma unroll 2
  for (int k0 = 0; k0 < K; k0 += 32) {
    bf16x8 av[4], bw[4];
#pragma unroll
    for (int mt = 0; mt < 4; ++mt)
      av[mt] = *(const bf16x8*)(g.A + (size_t)(m0 + mt * 16 + lr) * K + k0 + lh * 8);
#pragma unroll
    for (int nt = 0; nt < 4; ++nt) {
      int row = n0 + nt * 16 + lr;
      bw[nt] = (row < g.N) ? *(const bf16x8*)(g.Bw + (size_t)row * K + k0 + lh * 8) : bz;
    }
#pragma unroll
    for (int mt = 0; mt < 4; ++mt)
#pragma unroll
      for (int nt = 0; nt < 4; ++nt)
        acc[mt][nt] = __builtin_amdgcn_mfma_f32_16x16x32_bf16(av[mt], bw[nt], acc[mt][nt], 0, 0, 0);
  }

  if constexpr (EPI == 4) {
#pragma unroll
    for (int mt = 0; mt < 4; ++mt)
#pragma unroll
      for (int nt = 0; nt < 4; ++nt) {
        const int n = n0 + nt * 16 + lr;
        if (n < g.N) {
          const float bia = g.bias[n];
#pragma unroll
          for (int r = 0; r < 4; ++r) {
            const int m = m0 + mt * 16 + lh * 4 + r;
            const int bb = m & 63, s = m >> 6;
            g.outF[((size_t)bb * cM + n) * cS + s] = acc[mt][nt][r] + bia;
          }
        }
      }
  } else {
#pragma unroll
    for (int mt = 0; mt < 4; ++mt) {
#pragma unroll
      for (int nt = 0; nt < 4; ++nt) {
        const int n = n0 + nt * 16 + lr;
        if (n < g.N) {
          const float bia = g.bias[n];
#pragma unroll
          for (int r = 0; r < 4; ++r) {
            const int m = m0 + mt * 16 + lh * 4 + r;
            float v = acc[mt][nt][r] + bia;
            if constexpr (EPI == 0) {
              g.outF[(size_t)m * g.ldo + n] = v;
            } else {  // EPI==1: sgate epilogue
              float sg = sigm(v + g.auxF[(size_t)(m & 63) * g.ldo + n]);
              float st = (float)g.auxBf[(size_t)m * g.ldo + n];
              g.outBf[(size_t)m * g.ldo + n] = (bf16)(sg * st);
            }
          }
        }
      }
    }
  }
}

// ---------------- prep kernels ----------------
__global__ void cvt8_k(const float* __restrict__ wv, const float* __restrict__ wihf,
                       const float* __restrict__ whhf, const float* __restrict__ wihb,
                       const float* __restrict__ whhb, const float* __restrict__ w1,
                       const float* __restrict__ w2, const float* __restrict__ we,
                       bf16* __restrict__ dst) {
  size_t i = ((size_t)blockIdx.x * 256 + threadIdx.x) * 4;
  if (i >= TOT_W) return;
  const float* s;
  size_t off;
  if (i < OFF_WIHF) { s = wv; off = OFF_WV; }
  else if (i < OFF_WHHF) { s = wihf; off = OFF_WIHF; }
  else if (i < OFF_WIHB) { s = whhf; off = OFF_WHHF; }
  else if (i < OFF_WHHB) { s = wihb; off = OFF_WIHB; }
  else if (i < OFF_W1) { s = whhb; off = OFF_WHHB; }
  else if (i < OFF_W2) { s = w1; off = OFF_W1; }
  else if (i < OFF_WE) { s = w2; off = OFF_W2; }
  else { s = we; off = OFF_WE; }
  float4 v = *(const float4*)(s + (i - off));
  bf16x4 o;
  o[0] = (bf16)v.x; o[1] = (bf16)v.y; o[2] = (bf16)v.z; o[3] = (bf16)v.w;
  *(bf16x4*)(dst + i) = o;
}

__global__ void gather_k(const int* __restrict__ src, const float* __restrict__ emb,
                         bf16* __restrict__ embeds) {
  int i = blockIdx.x * 256 + threadIdx.x;
  int e = i & 255;
  int sb = i >> 8;
  int s = sb >> 6, b = sb & 63;
  int tok = src[b * cS + s];
  embeds[i] = (bf16)emb[(size_t)tok * cE + e];
}

// gate-interleaved decoder GRU weight
__global__ void build_wp_k(const float* __restrict__ Wih_c, const float* __restrict__ Whh_c,
                           const float* __restrict__ bih_c, const float* __restrict__ bhh_c,
                           bf16* __restrict__ Wp, float* __restrict__ bp) {
  int i = blockIdx.x * 256 + threadIdx.x;
  if (i >= cN4 * cKcat) return;
  int j = i / cKcat, c = i % cKcat;
  int bi = j >> 6, gg = (j >> 4) & 3, idx = j & 15;
  int u = bi * 16 + idx;
  float v;
  if (gg == 0) v = (c < 768) ? Wih_c[(size_t)u * 768 + c] : Whh_c[(size_t)u * 512 + (c - 768)];
  else if (gg == 1) v = (c < 768) ? Wih_c[(size_t)(512 + u) * 768 + c] : Whh_c[(size_t)(512 + u) * 512 + (c - 768)];
  else if (gg == 2) v = (c < 768) ? Wih_c[(size_t)(1024 + u) * 768 + c] : 0.f;
  else v = (c < 768) ? 0.f : Whh_c[(size_t)(1024 + u) * 512 + (c - 768)];
  Wp[i] = (bf16)v;
  if (c == 0) {
    float bb;
    if (gg == 0) bb = bih_c[u] + bhh_c[u];
    else if (gg == 1) bb = bih_c[512 + u] + bhh_c[512 + u];
    else if (gg == 2) bb = bih_c[1024 + u];
    else bb = bhh_c[1024 + u];
    bp[j] = bb;
  }
}

__global__ void concat_k(const float* __restrict__ hf, const float* __restrict__ hb,
                         bf16* __restrict__ hd_bf, float* __restrict__ hd_f) {
  int i = blockIdx.x * 256 + threadIdx.x;
  if (i >= cB * cH) return;
  int b = i >> 9, k = i & 511;
  float v = (k < 256) ? hf[b * 256 + k] : hb[b * 256 + (k - 256)];
  hd_bf[i] = (bf16)v;
  hd_f[i] = v;
}

// statesg[s][b][k] -> statesgT[b][k][s]
__global__ __launch_bounds__(256) void transp_k(const bf16* __restrict__ sg,
                                                bf16* __restrict__ sgT) {
  const int b = blockIdx.x, tid = threadIdx.x;
  __shared__ bf16 tile[64][520];
  for (int s0 = 0; s0 < cS; s0 += 64) {
    __syncthreads();
    for (int c = tid; c < 64 * 64; c += 256) {
      int row = c >> 6, col = c & 63;
      *(bf16x8*)(&tile[row][col * 8]) =
          *(const bf16x8*)(sg + ((size_t)(s0 + row) * cB + b) * cH + col * 8);
    }
    __syncthreads();
    for (int c = tid; c < 512 * 8; c += 256) {
      int k = c >> 3, sc = c & 7;
      bf16x8 v;
#pragma unroll
      for (int j = 0; j < 8; ++j) v[j] = tile[sc * 8 + j][k];
      *(bf16x8*)(sgT + ((size_t)b * cH + k) * cS + s0 + sc * 8) = v;
    }
  }
}

// ---------------- encoder GRU v5: reg-pipelined gi (1 step ahead), LDS = h only ----------------
__global__ __launch_bounds__(512, 1) void enc_rnn_k(
    const bf16* __restrict__ WhhF, const bf16* __restrict__ WhhB,
    const float* __restrict__ giF, const float* __restrict__ giB,
    const float* __restrict__ bhhF, const float* __restrict__ bhhB,
    float* __restrict__ hfin, bf16* __restrict__ states) {
  const int blk = blockIdx.x;
  const int dir = blk >> 2;
  const int bc = blk & 3;
  const bf16* Whh = dir ? WhhB : WhhF;
  const float* gi = dir ? giB : giF;
  const float* bhh = dir ? bhhB : bhhF;

  const int tid = threadIdx.x;
  const int lane = tid & 63, w = tid >> 6;
  const int lr = lane & 15, lh = lane >> 4;
  const int u0 = w * 32;

  bf16x8 Bf[6][8];
  float bh[6];
#pragma unroll
  for (int gg = 0; gg < 3; ++gg)
#pragma unroll
    for (int ut = 0; ut < 2; ++ut) {
      int nbase = gg * 256 + u0 + ut * 16;
#pragma unroll
      for (int kf = 0; kf < 8; ++kf)
        Bf[gg * 2 + ut][kf] = *(const bf16x8*)(Whh + (size_t)(nbase + lr) * 256 + kf * 32 + lh * 8);
      bh[gg * 2 + ut] = bhh[nbase + lr];
    }

  __shared__ bf16 hs[2][16][264];

  const float* gbase = gi + (size_t)(bc * 16 + lh * 4) * cG2 + u0 + lr;

  float hreg[2][4];
#pragma unroll
  for (int ut = 0; ut < 2; ++ut)
#pragma unroll
    for (int r = 0; r < 4; ++r) hreg[ut][r] = 0.f;

  float gvA[24], gvB[24];

  auto load_gv = [&](float (&gv)[24], int t2) {
    if (t2 >= cS) return;
    const int s2 = dir ? (cS - 1 - t2) : t2;
    const float* gs = gbase + (size_t)s2 * (cB * cG2);
#pragma unroll
    for (int ut = 0; ut < 2; ++ut)
#pragma unroll
      for (int r = 0; r < 4; ++r)
#pragma unroll
        for (int gg = 0; gg < 3; ++gg)
          gv[ut * 12 + r * 3 + gg] = gs[(size_t)r * cG2 + gg * 256 + ut * 16];
  };

  auto step = [&](int t, const float (&gv)[24]) {
    const int rb = t & 1, wb = rb ^ 1;
    bf16x8 av[8];
#pragma unroll
    for (int kf = 0; kf < 8; ++kf)
      av[kf] = *(const bf16x8*)(&hs[rb][lr][kf * 32 + lh * 8]);

    f32x4 acc[6];
#pragma unroll
    for (int j = 0; j < 6; ++j)
#pragma unroll
      for (int r = 0; r < 4; ++r) acc[j][r] = 0.f;

#pragma unroll
    for (int kf = 0; kf < 8; ++kf)
#pragma unroll
      for (int nt = 0; nt < 6; ++nt)
        acc[nt] = __builtin_amdgcn_mfma_f32_16x16x32_bf16(av[kf], Bf[nt][kf], acc[nt], 0, 0, 0);

#pragma unroll
    for (int ut = 0; ut < 2; ++ut) {
      const int u = u0 + ut * 16 + lr;
#pragma unroll
      for (int r = 0; r < 4; ++r) {
        const int b = lh * 4 + r;
        float rr = sigm(gv[ut * 12 + r * 3 + 0] + acc[ut][r] + bh[ut]);
        float zz = sigm(gv[ut * 12 + r * 3 + 1] + acc[2 + ut][r] + bh[2 + ut]);
        float nn = tanh_f(gv[ut * 12 + r * 3 + 2] + rr * (acc[4 + ut][r] + bh[4 + ut]));
        float hnew = (1.f - zz) * nn + zz * hreg[ut][r];
        hreg[ut][r] = hnew;
        hs[wb][b][u] = (bf16)hnew;
      }
    }

    // barrier WITHOUT vmcnt(0) drain: in-flight prefetch loads/stores cross it
    asm volatile("s_waitcnt lgkmcnt(0)" ::: "memory");
    __builtin_amdgcn_s_barrier();

    {  // coalesced states store (off critical path)
      const int s_src = dir ? (cS - 1 - t) : t;
      const int row = tid >> 5, c8 = tid & 31;
      bf16x8 v = *(const bf16x8*)(&hs[wb][row][c8 * 8]);
      *(bf16x8*)(states + ((size_t)s_src * cB + bc * 16 + row) * cH + dir * 256 + c8 * 8) = v;
    }
  };

  load_gv(gvA, 0);
  for (int i = tid; i < 16 * 264; i += 512) ((bf16*)hs[0])[i] = (bf16)0.f;
  __syncthreads();

  for (int t = 0; t < cS; t += 2) {
    load_gv(gvB, t + 1);
    step(t, gvA);
    load_gv(gvA, t + 2);
    step(t + 1, gvB);
  }

#pragma unroll
  for (int ut = 0; ut < 2; ++ut)
#pragma unroll
    for (int r = 0; r < 4; ++r)
      hfin[((size_t)dir * cB + bc * 16 + lh * 4 + r) * cH2 + u0 + ut * 16 + lr] = hreg[ut][r];
}

// ---------------- decoder bodies ----------------
DEVFN void logits_tile(int w, int lane, const bf16* __restrict__ A, const bf16* __restrict__ Bw,
                       const float* __restrict__ bias, float* __restrict__ partials) {
  if (w >= cNTV) return;
  const int n0 = w << 6, lr = lane & 15, lh = lane >> 4;
  f32x4 acc[4][4];
#pragma unroll
  for (int i = 0; i < 4; ++i)
#pragma unroll
    for (int j = 0; j < 4; ++j)
#pragma unroll
      for (int r = 0; r < 4; ++r) acc[i][j][r] = 0.f;
  bf16x8 bz;
#pragma unroll
  for (int q = 0; q < 8; ++q) bz[q] = (bf16)0.f;

#pragma unroll 2
  for (int k0 = 0; k0 < cH; k0 += 32) {
    bf16x8 av[4], bw[4];
#pragma unroll
    for (int mt = 0; mt < 4; ++mt)
      av[mt] = *(const bf16x8*)(A + (size_t)(mt * 16 + lr) * cH + k0 + lh * 8);
#pragma unroll
    for (int nt = 0; nt < 4; ++nt) {
      int row = n0 + nt * 16 + lr;
      bw[nt] = (row < cV) ? *(const bf16x8*)(Bw + (size_t)row * cH + k0 + lh * 8) : bz;
    }
#pragma unroll
    for (int mt = 0; mt < 4; ++mt)
#pragma unroll
      for (int nt = 0; nt < 4; ++nt)
        acc[mt][nt] = __builtin_amdgcn_mfma_f32_16x16x32_bf16(av[mt], bw[nt], acc[mt][nt], 0, 0, 0);
  }

#pragma unroll
  for (int mt = 0; mt < 4; ++mt) {
#pragma unroll
    for (int r = 0; r < 4; ++r) {
      const int m = mt * 16 + lh * 4 + r;
      float vv[4];
      float mx = -3.4e38f;
#pragma unroll
      for (int nt = 0; nt < 4; ++nt) {
        int n = n0 + nt * 16 + lr;
        float v = (n < cV) ? (acc[mt][nt][r] + bias[n]) : -3.4e38f;
        vv[nt] = v;
        mx = fmaxf(mx, v);
      }
#pragma unroll
      for (int msk = 1; msk < 16; msk <<= 1) mx = fmaxf(mx, __shfl_xor(mx, msk));
      float sm = 0.f;
#pragma unroll
      for (int nt = 0; nt < 4; ++nt) {
        int n = n0 + nt * 16 + lr;
        if (n < cV) sm += __expf(vv[nt] - mx);
      }
#pragma unroll
      for (int msk = 1; msk < 16; msk <<= 1) sm += __shfl_xor(sm, msk);
      if (lr == 0) {
        float* p = partials + ((size_t)w * 64 + m) * 2;
        p[0] = mx;
        p[1] = sm;
      }
    }
  }
}

// K1: blocks [0,cLB) logits(t-1); blocks [cLB,cLB+64) attn(t)
__global__ __launch_bounds__(256) void dec_k1(
    const bf16* __restrict__ hin, const bf16* __restrict__ Wv_b, const float* __restrict__ bv,
    float* __restrict__ partials,
    const float* __restrict__ Wd, const float* __restrict__ bd,
    const float* __restrict__ Wo, const float* __restrict__ bo,
    const float* __restrict__ epT, const bf16* __restrict__ sgT,
    const float* __restrict__ emb, const int* __restrict__ trg,
    int t, bf16* __restrict__ xh) {
  const int tid = threadIdx.x;
  const int lane = tid & 63, wid = tid >> 6;

  if (blockIdx.x < cLB) {
    if (t == 0) return;
    logits_tile(blockIdx.x * 4 + wid, lane, hin, Wv_b, bv, partials);
    return;
  }
  if (t >= cT - 1) return;
  const int b = blockIdx.x - cLB;

  __shared__ float hsh[512];
  __shared__ float dsh[100];
  __shared__ float esh[400];
  __shared__ float red[16];

  for (int k = tid; k < 512; k += 256) hsh[k] = (float)hin[b * 512 + k];
  __syncthreads();

  for (int jj = 0; jj < 25; ++jj) {
    const int j = wid * 25 + jj;
    const float* wr = Wd + (size_t)j * 512 + lane * 8;
    float a = 0.f;
#pragma unroll
    for (int q = 0; q < 8; ++q) a += wr[q] * hsh[lane * 8 + q];
#pragma unroll
    for (int m = 1; m < 64; m <<= 1) a += __shfl_xor(a, m);
    if (lane == 0) dsh[j] = a + bd[j];
  }
  __syncthreads();

  const float bo0 = bo[0];
  const float* ep0 = epT + (size_t)b * cM * cS;
  float e0, e1 = -3.4e38f;
  {
    const float* p = ep0 + tid;
    float a = bo0;
#pragma unroll 4
    for (int j = 0; j < 100; ++j) a += Wo[j] * tanh_f(dsh[j] + p[j * cS]);
    e0 = a;
  }
  if (tid < 144) {
    const float* p = ep0 + 256 + tid;
    float a = bo0;
#pragma unroll 4
    for (int j = 0; j < 100; ++j) a += Wo[j] * tanh_f(dsh[j] + p[j * cS]);
    e1 = a;
  }
  float mx = fmaxf(e0, e1);
#pragma unroll
  for (int msk = 1; msk < 64; msk <<= 1) mx = fmaxf(mx, __shfl_xor(mx, msk));
  if (lane == 0) red[wid] = mx;
  __syncthreads();
  mx = fmaxf(fmaxf(red[0], red[1]), fmaxf(red[2], red[3]));

  float a0 = __expf(e0 - mx);
  float a1 = (tid < 144) ? __expf(e1 - mx) : 0.f;
  esh[tid] = a0;
  if (tid < 144) esh[tid + 256] = a1;
  float sm = a0 + a1;
#pragma unroll
  for (int msk = 1; msk < 64; msk <<= 1) sm += __shfl_xor(sm, msk);
  if (lane == 0) red[8 + wid] = sm;
  __syncthreads();
  const float inv = 1.f / (red[8] + red[9] + red[10] + red[11]);

  // context via statesgT[b][k][s]: thread owns units tid and tid+256
  {
    const bf16* sp0 = sgT + ((size_t)b * cH + tid) * cS;
    const bf16* sp1 = sp0 + (size_t)256 * cS;
    float c0 = 0.f, c1 = 0.f;
    for (int s = 0; s < cS; s += 8) {
      bf16x8 v0 = *(const bf16x8*)(sp0 + s);
      bf16x8 v1 = *(const bf16x8*)(sp1 + s);
#pragma unroll
      for (int j = 0; j < 8; ++j) {
        float wj = esh[s + j];
        c0 += wj * (float)v0[j];
        c1 += wj * (float)v1[j];
      }
    }
    xh[(size_t)b * cKcat + tid] = (bf16)(c0 * inv);
    xh[(size_t)b * cKcat + 256 + tid] = (bf16)(c1 * inv);
  }
  const int tok = trg[b * cT + t];
  xh[(size_t)b * cKcat + 512 + tid] = (bf16)emb[(size_t)tok * cE + tid];
  for (int k = tid; k < 512; k += 256) xh[(size_t)b * cKcat + 768 + k] = hin[b * 512 + k];
}

// K2: blocks [0,8) gru(t); blocks [8,72) rowloss(t-1)
__global__ __launch_bounds__(256) void dec_k2(
    const bf16* __restrict__ xh, const bf16* __restrict__ Wp, const float* __restrict__ bp,
    const float* __restrict__ hin_f, float* __restrict__ hout_f, bf16* __restrict__ hout_bf,
    const float* __restrict__ partials, const bf16* __restrict__ hprev,
    const float* __restrict__ Wv, const float* __restrict__ bv,
    const int* __restrict__ trg, int t,
    float* __restrict__ rnll, float* __restrict__ rw) {
  const int tid = threadIdx.x;
  const int lane = tid & 63, wid = tid >> 6;

  if (blockIdx.x < 8) {
    if (t >= cT - 1) return;
    // fused GRU cell: 64x64 tile of gate-interleaved N
    const int w = blockIdx.x * 4 + wid;
    const int n0 = w << 6, lr = lane & 15, lh = lane >> 4;
    f32x4 acc[4][4];
#pragma unroll
    for (int i = 0; i < 4; ++i)
#pragma unroll
      for (int j = 0; j < 4; ++j)
#pragma unroll
        for (int r = 0; r < 4; ++r) acc[i][j][r] = 0.f;
#pragma unroll 2
    for (int k0 = 0; k0 < cKcat; k0 += 32) {
      bf16x8 av[4], bw[4];
#pragma unroll
      for (int mt = 0; mt < 4; ++mt)
        av[mt] = *(const bf16x8*)(xh + (size_t)(mt * 16 + lr) * cKcat + k0 + lh * 8);
#pragma unroll
      for (int nt = 0; nt < 4; ++nt)
        bw[nt] = *(const bf16x8*)(Wp + (size_t)(n0 + nt * 16 + lr) * cKcat + k0 + lh * 8);
#pragma unroll
      for (int mt = 0; mt < 4; ++mt)
#pragma unroll
        for (int nt = 0; nt < 4; ++nt)
          acc[mt][nt] = __builtin_amdgcn_mfma_f32_16x16x32_bf16(av[mt], bw[nt], acc[mt][nt], 0, 0, 0);
    }
    const int u = (n0 >> 2) + lr;
    const float br = bp[n0 + lr];
    const float bz2 = bp[n0 + 16 + lr];
    const float bi2 = bp[n0 + 32 + lr];
    const float bh2 = bp[n0 + 48 + lr];
#pragma unroll
    for (int mt = 0; mt < 4; ++mt)
#pragma unroll
      for (int r = 0; r < 4; ++r) {
        const int bb = mt * 16 + lh * 4 + r;
        float rr = sigm(acc[mt][0][r] + br);
        float zz = sigm(acc[mt][1][r] + bz2);
        float nn = tanh_f(acc[mt][2][r] + bi2 + rr * (acc[mt][3][r] + bh2));
        float h2v = (1.f - zz) * nn + zz * hin_f[(size_t)bb * cH + u];
        hout_f[(size_t)bb * cH + u] = h2v;
        hout_bf[(size_t)bb * cH + u] = (bf16)h2v;
      }
    return;
  }

  if (t == 0) return;
  const int b = blockIdx.x - 8;
  const int step = t - 1;
  float mx = -3.4e38f, sm = 0.f;
  for (int p = tid; p < cNTV; p += 256) {
    const float* pp = partials + ((size_t)p * 64 + b) * 2;
    float m2 = pp[0], s2 = pp[1];
    if (m2 > mx) { sm = sm * __expf(mx - m2) + s2; mx = m2; }
    else sm += s2 * __expf(m2 - mx);
  }
#pragma unroll
  for (int msk = 1; msk < 64; msk <<= 1) {
    float om = __shfl_xor(mx, msk), os = __shfl_xor(sm, msk);
    if (om > mx) { sm = sm * __expf(mx - om) + os; mx = om; }
    else sm += os * __expf(om - mx);
  }
  __shared__ float sM[4], sS[4], sD[4];
  if (lane == 0) { sM[wid] = mx; sS[wid] = sm; }

  const int tok = trg[b * cT + step];
  float dot;
  {
    const float2 wq = *(const float2*)(Wv + (size_t)tok * cH + tid * 2);
    const bf16x2 hq = *(const bf16x2*)(hprev + (size_t)b * cH + tid * 2);
    dot = (float)hq[0] * wq.x + (float)hq[1] * wq.y;
  }
#pragma unroll
  for (int msk = 1; msk < 64; msk <<= 1) dot += __shfl_xor(dot, msk);
  if (lane == 0) sD[wid] = dot;
  __syncthreads();
  if (tid == 0) {
    float MM = fmaxf(fmaxf(sM[0], sM[1]), fmaxf(sM[2], sM[3]));
    float SS = 0.f;
#pragma unroll
    for (int q = 0; q < 4; ++q) SS += sS[q] * __expf(sM[q] - MM);
    float d = sD[0] + sD[1] + sD[2] + sD[3];
    float lse = MM + __logf(SS);
    float nll = lse - (d + bv[tok]);
    float wgt = (tok != cEOS) ? 1.f : 0.f;
    rnll[step * cB + b] = wgt * nll;
    rw[step * cB + b] = wgt;
  }
}

__global__ __launch_bounds__(64) void final_loss_k(const float* __restrict__ rnll,
                                                   const float* __restrict__ rw,
                                                   float* __restrict__ out) {
  __shared__ float sl[32];
  const int t = threadIdx.x;
  if (t < cT - 1) {
    float a = 0.f, d = 0.f;
    for (int b = 0; b < cB; ++b) { a += rnll[t * cB + b]; d += rw[t * cB + b]; }
    sl[t] = a / d;
  }
  __syncthreads();
  if (t == 0) {
    float s = 0.f;
    for (int i = 0; i < cT - 1; ++i) s += sl[i];
    out[0] = s / (float)cB;
  }
}

// ---------------- host ----------------
extern "C" void kernel_launch(void* const* d_in, const int* in_sizes, int n_in,
                              void* d_out, int out_size, void* d_ws, size_t ws_size,
                              hipStream_t stream) {
  (void)in_sizes; (void)n_in; (void)out_size; (void)ws_size;
  const int* src = (const int*)d_in[0];
  const int* trg = (const int*)d_in[1];
  const float* emb = (const float*)d_in[2];
  const float* Wih_f = (const float*)d_in[3];
  const float* Whh_f = (const float*)d_in[4];
  const float* bih_f = (const float*)d_in[5];
  const float* bhh_f = (const float*)d_in[6];
  const float* Wih_b = (const float*)d_in[7];
  const float* Whh_b = (const float*)d_in[8];
  const float* bih_b = (const float*)d_in[9];
  const float* bhh_b = (const float*)d_in[10];
  const float* W1 = (const float*)d_in[11];
  const float* b1 = (const float*)d_in[12];
  const float* W2 = (const float*)d_in[13];
  const float* b2 = (const float*)d_in[14];
  const float* Wd = (const float*)d_in[15];
  const float* bd = (const float*)d_in[16];
  const float* We = (const float*)d_in[17];
  const float* be = (const float*)d_in[18];
  const float* Wo = (const float*)d_in[19];
  const float* bo = (const float*)d_in[20];
  const float* Wih_c = (const float*)d_in[21];
  const float* Whh_c = (const float*)d_in[22];
  const float* bih_c = (const float*)d_in[23];
  const float* bhh_c = (const float*)d_in[24];
  const float* Wv = (const float*)d_in[25];
  const float* bv = (const float*)d_in[26];
  float* out = (float*)d_out;

  char* ws = (char*)d_ws;
  size_t off = 0;
  auto carve = [&](size_t bytes) -> void* {
    void* p = ws + off;
    off += (bytes + 255) & ~(size_t)255;
    return p;
  };
  bf16* wcat = (bf16*)carve(TOT_W * 2);
  bf16* Wv_b = wcat + OFF_WV;
  bf16* Wihf_b = wcat + OFF_WIHF;
  bf16* Whhf_b = wcat + OFF_WHHF;
  bf16* Wihb_b = wcat + OFF_WIHB;
  bf16* Whhb_b = wcat + OFF_WHHB;
  bf16* W1_b = wcat + OFF_W1;
  bf16* W2_b = wcat + OFF_W2;
  bf16* We_b = wcat + OFF_WE;
  bf16* Wp_b = (bf16*)carve((size_t)cN4 * cKcat * 2);
  float* bp = (float*)carve((size_t)cN4 * 4);
  bf16* embeds = (bf16*)carve((size_t)cSB * cE * 2);
  float* gi_f = (float*)carve((size_t)cSB * cG2 * 4);
  float* gi_b = (float*)carve((size_t)cSB * cG2 * 4);
  bf16* states = (bf16*)carve((size_t)cSB * cH * 2);
  bf16* statesg = (bf16*)carve((size_t)cSB * cH * 2);
  bf16* statesgT = (bf16*)carve((size_t)cSB * cH * 2);
  float* hfin = (float*)carve((size_t)2 * cB * cH2 * 4);
  bf16* hdec0_bf = (bf16*)carve((size_t)cB * cH * 2);
  float* hdec0_f = (float*)carve((size_t)cB * cH * 4);
  bf16* hping_bf0 = (bf16*)carve((size_t)cB * cH * 2);
  bf16* hping_bf1 = (bf16*)carve((size_t)cB * cH * 2);
  float* hping_f0 = (float*)carve((size_t)cB * cH * 4);
  float* hping_f1 = (float*)carve((size_t)cB * cH * 4);
  float* hw2 = (float*)carve((size_t)cB * cH * 4);
  float* epT = (float*)carve((size_t)cB * cM * cS * 4);
  bf16* xh = (bf16*)carve((size_t)cB * cKcat * 2);
  float* partials = (float*)carve((size_t)cNTV * 64 * 2 * 4);
  float* rnll = (float*)carve((size_t)(cT - 1) * cB * 4);
  float* rw = (float*)carve((size_t)(cT - 1) * cB * 4);

  auto gemm0 = [&](const bf16* A, const bf16* Bm, const float* bias, float* outF,
                   int M, int N, int K, int ldo) {
    GArgs ga{A, Bm, bias, outF, nullptr, nullptr, nullptr, nullptr, M, N, K, ldo};
    int waves = (M / 64) * ((N + 63) / 64);
    gemm64_k<0><<<dim3((waves + 3) / 4), dim3(256), 0, stream>>>(ga);
  };

  // weight prep
  cvt8_k<<<dim3((TOT_W / 4 + 255) / 256), dim3(256), 0, stream>>>(
      Wv, Wih_f, Whh_f, Wih_b, Whh_b, W1, W2, We, wcat);
  build_wp_k<<<dim3((cN4 * cKcat + 255) / 256), dim3(256), 0, stream>>>(
      Wih_c, Whh_c, bih_c, bhh_c, Wp_b, bp);

  // encoder
  gather_k<<<dim3(cSB * cE / 256), dim3(256), 0, stream>>>(src, emb, embeds);
  gemm0(embeds, Wihf_b, bih_f, gi_f, cSB, cG2, cE, cG2);
  gemm0(embeds, Wihb_b, bih_b, gi_b, cSB, cG2, cE, cG2);
  enc_rnn_k<<<dim3(8), dim3(512), 0, stream>>>(Whhf_b, Whhb_b, gi_f, gi_b, bhh_f, bhh_b,
                                               hfin, states);
  concat_k<<<dim3((cB * cH + 255) / 256), dim3(256), 0, stream>>>(
      hfin, hfin + (size_t)cB * cH2, hdec0_bf, hdec0_f);
  gemm0(hdec0_bf, W2_b, b2, hw2, cB, cH, cH, cH);
  {  // sgate: statesg = sigmoid(states@W1^T + b1 + hw2) * states
    GArgs ga{states, W1_b, b1, nullptr, statesg, hw2, states, nullptr, cSB, cH, cH, cH};
    int waves = (cSB / 64) * (cH / 64);
    gemm64_k<1><<<dim3((waves + 3) / 4), dim3(256), 0, stream>>>(ga);
  }
  {  // encproj, transposed: epT[b][j][s]
    GArgs ga{statesg, We_b, be, epT, nullptr, nullptr, nullptr, nullptr, cSB, cM, cH, 0};
    int waves = (cSB / 64) * ((cM + 63) / 64);
    gemm64_k<4><<<dim3((waves + 3) / 4), dim3(256), 0, stream>>>(ga);
  }
  transp_k<<<dim3(cB), dim3(256), 0, stream>>>(statesg, statesgT);

  // decoder: t=0..24; K1 = attn(t) || logits(t-1); K2 = gru(t) || rowloss(t-1)
  for (int t = 0; t < cT; ++t) {
    const bf16* hin_bf = (t == 0) ? hdec0_bf : ((t & 1) ? hping_bf0 : hping_bf1);
    const float* hin_f = (t == 0) ? hdec0_f : ((t & 1) ? hping_f0 : hping_f1);
    bf16* hout_bf = (t & 1) ? hping_bf1 : hping_bf0;
    float* hout_f = (t & 1) ? hping_f1 : hping_f0;

    dec_k1<<<dim3(cLB + cB), dim3(256), 0, stream>>>(
        hin_bf, Wv_b, bv, partials, Wd, bd, Wo, bo, epT, statesgT, emb, trg, t, xh);
    dec_k2<<<dim3(72), dim3(256), 0, stream>>>(
        xh, Wp_b, bp, hin_f, hout_f, hout_bf, partials, hin_bf, Wv, bv, trg, t, rnll, rw);
  }
  final_loss_k<<<dim3(1), dim3(64), 0, stream>>>(rnll, rw, out);
}

// Round 6
// 4271.886 us; speedup vs baseline: 4.9013x; 4.9013x over previous
//
#include <hip/hip_runtime.h>

typedef __bf16 bf16;
typedef bf16 bf16x2 __attribute__((ext_vector_type(2)));
typedef bf16 bf16x4 __attribute__((ext_vector_type(4)));
typedef bf16 bf16x8 __attribute__((ext_vector_type(8)));
typedef float f32x4 __attribute__((ext_vector_type(4)));

#define DEVFN __device__ __forceinline__

constexpr int cV = 50000, cE = 256, cH = 512, cM = 100, cH2 = 256;
constexpr int cB = 64, cS = 400, cT = 25, cEOS = 2;
constexpr int cSB = cS * cB;          // 25600
constexpr int cG2 = 3 * cH2;          // 768
constexpr int cGP = 772;              // gi LDS row pad (772%32=4 -> 2-way, free)
constexpr int cKcat = 1280;           // [c(512) | wemb(256) | h(512)]
constexpr int cN4 = 2048;             // interleaved r,z,inn,hn rows
constexpr int cNTV = (cV + 63) / 64;  // 782
constexpr int cTD = cT - 1;           // 24 decode steps
constexpr int cVT = cV / 16;          // 3125 Wv row-tiles (exact)

// concatenated bf16 weight cache offsets (elements)
constexpr size_t OFF_WV = 0;
constexpr size_t N_WV = (size_t)cV * cH;
constexpr size_t OFF_WIHF = OFF_WV + N_WV;
constexpr size_t N_WIH = (size_t)cG2 * cE;
constexpr size_t OFF_WHHF = OFF_WIHF + N_WIH;
constexpr size_t N_WHH = (size_t)cG2 * cH2;
constexpr size_t OFF_WIHB = OFF_WHHF + N_WHH;
constexpr size_t OFF_WHHB = OFF_WIHB + N_WIH;
constexpr size_t OFF_W1 = OFF_WHHB + N_WHH;
constexpr size_t N_WSQ = (size_t)cH * cH;
constexpr size_t OFF_W2 = OFF_W1 + N_WSQ;
constexpr size_t OFF_WE = OFF_W2 + N_WSQ;
constexpr size_t N_WE = (size_t)cM * cH;
constexpr size_t TOT_W = OFF_WE + N_WE;

struct GArgs {
  const bf16* A; const bf16* Bw; const float* bias;
  float* outF; bf16* outBf;
  const float* auxF; const bf16* auxBf;
  int M, N, K, ldo;
};

DEVFN float sigm(float x) { return 1.f / (1.f + __expf(-x)); }
DEVFN float tanh_f(float x) {
  float e2 = __expf(2.f * x);
  return 1.f - 2.f / (e2 + 1.f);
}

DEVFN void gload_lds16(const void* g, void* l) {
  __builtin_amdgcn_global_load_lds(
      (const __attribute__((address_space(1))) void*)g,
      (__attribute__((address_space(3))) void*)l, 16, 0, 0);
}

// ---------------- generic 64x64-per-wave MFMA GEMM: C = A(MxK) * B(NxK)^T ----------------
// EPI 0: outF = acc + bias ; EPI 1: sgate -> bf16 ; EPI 4: transposed epT[b][n][s]
template <int EPI>
__global__ __launch_bounds__(256) void gemm64_k(GArgs g) {
  const int tid = threadIdx.x;
  const int w = blockIdx.x * 4 + (tid >> 6);
  const int tM = g.M >> 6;
  const int tN = (g.N + 63) >> 6;
  if (w >= tM * tN) return;
  const int im = w % tM, in = w / tM;
  const int m0 = im << 6, n0 = in << 6;
  const int lane = tid & 63, lr = lane & 15, lh = lane >> 4;

  f32x4 acc[4][4];
#pragma unroll
  for (int i = 0; i < 4; ++i)
#pragma unroll
    for (int j = 0; j < 4; ++j)
#pragma unroll
      for (int r = 0; r < 4; ++r) acc[i][j][r] = 0.f;

  bf16x8 bz;
#pragma unroll
  for (int q = 0; q < 8; ++q) bz[q] = (bf16)0.f;

  const int K = g.K;
#pragma unroll 2
  for (int k0 = 0; k0 < K; k0 += 32) {
    bf16x8 av[4], bw[4];
#pragma unroll
    for (int mt = 0; mt < 4; ++mt)
      av[mt] = *(const bf16x8*)(g.A + (size_t)(m0 + mt * 16 + lr) * K + k0 + lh * 8);
#pragma unroll
    for (int nt = 0; nt < 4; ++nt) {
      int row = n0 + nt * 16 + lr;
      bw[nt] = (row < g.N) ? *(const bf16x8*)(g.Bw + (size_t)row * K + k0 + lh * 8) : bz;
    }
#pragma unroll
    for (int mt = 0; mt < 4; ++mt)
#pragma unroll
      for (int nt = 0; nt < 4; ++nt)
        acc[mt][nt] = __builtin_amdgcn_mfma_f32_16x16x32_bf16(av[mt], bw[nt], acc[mt][nt], 0, 0, 0);
  }

  if constexpr (EPI == 4) {
#pragma unroll
    for (int mt = 0; mt < 4; ++mt)
#pragma unroll
      for (int nt = 0; nt < 4; ++nt) {
        const int n = n0 + nt * 16 + lr;
        if (n < g.N) {
          const float bia = g.bias[n];
#pragma unroll
          for (int r = 0; r < 4; ++r) {
            const int m = m0 + mt * 16 + lh * 4 + r;
            const int bb = m & 63, s = m >> 6;
            g.outF[((size_t)bb * cM + n) * cS + s] = acc[mt][nt][r] + bia;
          }
        }
      }
  } else {
#pragma unroll
    for (int mt = 0; mt < 4; ++mt) {
#pragma unroll
      for (int nt = 0; nt < 4; ++nt) {
        const int n = n0 + nt * 16 + lr;
        if (n < g.N) {
          const float bia = g.bias[n];
#pragma unroll
          for (int r = 0; r < 4; ++r) {
            const int m = m0 + mt * 16 + lh * 4 + r;
            float v = acc[mt][nt][r] + bia;
            if constexpr (EPI == 0) {
              g.outF[(size_t)m * g.ldo + n] = v;
            } else {  // EPI==1: sgate epilogue
              float sg = sigm(v + g.auxF[(size_t)(m & 63) * g.ldo + n]);
              float st = (float)g.auxBf[(size_t)m * g.ldo + n];
              g.outBf[(size_t)m * g.ldo + n] = (bf16)(sg * st);
            }
          }
        }
      }
    }
  }
}

// ---------------- prep kernels ----------------
// Wv is stored MFMA-fragment-swizzled: element(row,col) ->
//   ((tile*16 + kc)*64 + lr*4 + lh)*8 + e   with tile=row>>4, lr=row&15,
//   kc=col>>5, lh=(col>>3)&3, e=col&7  -> B-fragment load = 1KB coalesced.
__global__ void cvt8_k(const float* __restrict__ wv, const float* __restrict__ wihf,
                       const float* __restrict__ whhf, const float* __restrict__ wihb,
                       const float* __restrict__ whhb, const float* __restrict__ w1,
                       const float* __restrict__ w2, const float* __restrict__ we,
                       bf16* __restrict__ dst) {
  size_t i = ((size_t)blockIdx.x * 256 + threadIdx.x) * 4;
  if (i >= TOT_W) return;
  if (i < OFF_WIHF) {  // Wv, swizzled
    float4 v = *(const float4*)(wv + i);
    size_t row = i >> 9, col = i & 511;
    size_t tile = row >> 4, lr = row & 15, kc = col >> 5, lh = (col >> 3) & 3, e = col & 7;
    size_t d = ((tile * 16 + kc) * 64 + lr * 4 + lh) * 8 + e;
    bf16x4 o;
    o[0] = (bf16)v.x; o[1] = (bf16)v.y; o[2] = (bf16)v.z; o[3] = (bf16)v.w;
    *(bf16x4*)(dst + d) = o;
    return;
  }
  const float* s;
  size_t off;
  if (i < OFF_WHHF) { s = wihf; off = OFF_WIHF; }
  else if (i < OFF_WIHB) { s = whhf; off = OFF_WHHF; }
  else if (i < OFF_WHHB) { s = wihb; off = OFF_WIHB; }
  else if (i < OFF_W1) { s = whhb; off = OFF_WHHB; }
  else if (i < OFF_W2) { s = w1; off = OFF_W1; }
  else if (i < OFF_WE) { s = w2; off = OFF_W2; }
  else { s = we; off = OFF_WE; }
  float4 v = *(const float4*)(s + (i - off));
  bf16x4 o;
  o[0] = (bf16)v.x; o[1] = (bf16)v.y; o[2] = (bf16)v.z; o[3] = (bf16)v.w;
  *(bf16x4*)(dst + i) = o;
}

__global__ void gather_k(const int* __restrict__ src, const float* __restrict__ emb,
                         bf16* __restrict__ embeds) {
  int i = blockIdx.x * 256 + threadIdx.x;
  int e = i & 255;
  int sb = i >> 8;
  int s = sb >> 6, b = sb & 63;
  int tok = src[b * cS + s];
  embeds[i] = (bf16)emb[(size_t)tok * cE + e];
}

// gate-interleaved + fragment-swizzled decoder GRU weight (K=1280 -> 40 k-chunks)
__global__ void build_wp_k(const float* __restrict__ Wih_c, const float* __restrict__ Whh_c,
                           const float* __restrict__ bih_c, const float* __restrict__ bhh_c,
                           bf16* __restrict__ Wp, float* __restrict__ bp) {
  int i = blockIdx.x * 256 + threadIdx.x;
  if (i >= cN4 * cKcat) return;
  int j = i / cKcat, c = i % cKcat;
  int bi = j >> 6, gg = (j >> 4) & 3, idx = j & 15;
  int u = bi * 16 + idx;
  float v;
  if (gg == 0) v = (c < 768) ? Wih_c[(size_t)u * 768 + c] : Whh_c[(size_t)u * 512 + (c - 768)];
  else if (gg == 1) v = (c < 768) ? Wih_c[(size_t)(512 + u) * 768 + c] : Whh_c[(size_t)(512 + u) * 512 + (c - 768)];
  else if (gg == 2) v = (c < 768) ? Wih_c[(size_t)(1024 + u) * 768 + c] : 0.f;
  else v = (c < 768) ? 0.f : Whh_c[(size_t)(1024 + u) * 512 + (c - 768)];
  {
    size_t tile = (size_t)j >> 4, lr = j & 15, kc = c >> 5, lh = (c >> 3) & 3, e = c & 7;
    Wp[((tile * 40 + kc) * 64 + lr * 4 + lh) * 8 + e] = (bf16)v;
  }
  if (c == 0) {
    float bb;
    if (gg == 0) bb = bih_c[u] + bhh_c[u];
    else if (gg == 1) bb = bih_c[512 + u] + bhh_c[512 + u];
    else if (gg == 2) bb = bih_c[1024 + u];
    else bb = bhh_c[1024 + u];
    bp[j] = bb;
  }
}

__global__ void concat_k(const float* __restrict__ hf, const float* __restrict__ hb,
                         bf16* __restrict__ hd_bf, float* __restrict__ hd_f) {
  int i = blockIdx.x * 256 + threadIdx.x;
  if (i >= cB * cH) return;
  int b = i >> 9, k = i & 511;
  float v = (k < 256) ? hf[b * 256 + k] : hb[b * 256 + (k - 256)];
  hd_bf[i] = (bf16)v;
  hd_f[i] = v;
}

// statesg[s][b][k] -> statesgT[b][k][s]
__global__ __launch_bounds__(256) void transp_k(const bf16* __restrict__ sg,
                                                bf16* __restrict__ sgT) {
  const int b = blockIdx.x, tid = threadIdx.x;
  __shared__ bf16 tile[64][520];
  for (int s0 = 0; s0 < cS; s0 += 64) {
    __syncthreads();
    for (int c = tid; c < 64 * 64; c += 256) {
      int row = c >> 6, col = c & 63;
      *(bf16x8*)(&tile[row][col * 8]) =
          *(const bf16x8*)(sg + ((size_t)(s0 + row) * cB + b) * cH + col * 8);
    }
    __syncthreads();
    for (int c = tid; c < 512 * 8; c += 256) {
      int k = c >> 3, sc = c & 7;
      bf16x8 v;
#pragma unroll
      for (int j = 0; j < 8; ++j) v[j] = tile[sc * 8 + j][k];
      *(bf16x8*)(sgT + ((size_t)b * cH + k) * cS + s0 + sc * 8) = v;
    }
  }
}

// ---------------- encoder GRU v3 (VERBATIM round-3: measured 1412us) ----------------
__global__ __launch_bounds__(512, 1) void enc_rnn_k(
    const bf16* __restrict__ WhhF, const bf16* __restrict__ WhhB,
    const float* __restrict__ giF, const float* __restrict__ giB,
    const float* __restrict__ bhhF, const float* __restrict__ bhhB,
    float* __restrict__ hfin, bf16* __restrict__ states) {
  const int blk = blockIdx.x;
  const int dir = blk >> 2;
  const int bc = blk & 3;
  const bf16* Whh = dir ? WhhB : WhhF;
  const float* gi = dir ? giB : giF;
  const float* bhh = dir ? bhhB : bhhF;

  const int tid = threadIdx.x;
  const int lane = tid & 63, w = tid >> 6;
  const int lr = lane & 15, lh = lane >> 4;
  const int u0 = w * 32;

  bf16x8 Bf[6][8];
  float bh[6];
#pragma unroll
  for (int gg = 0; gg < 3; ++gg)
#pragma unroll
    for (int ut = 0; ut < 2; ++ut) {
      int nbase = gg * 256 + u0 + ut * 16;
#pragma unroll
      for (int kf = 0; kf < 8; ++kf)
        Bf[gg * 2 + ut][kf] = *(const bf16x8*)(Whh + (size_t)(nbase + lr) * 256 + kf * 32 + lh * 8);
      bh[gg * 2 + ut] = bhh[nbase + lr];
    }

  __shared__ float gilds[2][16][cGP];
  __shared__ bf16 hs[2][16][264];

  auto prefetch = [&](int t2) {
    if (t2 >= cS) return;
    const int s2 = dir ? (cS - 1 - t2) : t2;
    const int buf = t2 & 1;
#pragma unroll
    for (int rr2 = 0; rr2 < 2; ++rr2) {
      const int row = w * 2 + rr2;
      const char* srcb = (const char*)(gi + ((size_t)s2 * cB + bc * 16 + row) * cG2);
      char* dstb = (char*)&gilds[buf][row][0];
#pragma unroll
      for (int c = 0; c < 3; ++c)
        gload_lds16(srcb + c * 1024 + lane * 16, dstb + c * 1024);
    }
  };

  float hreg[2][4];
#pragma unroll
  for (int ut = 0; ut < 2; ++ut)
#pragma unroll
    for (int r = 0; r < 4; ++r) hreg[ut][r] = 0.f;

  prefetch(0);
  for (int i = tid; i < 16 * 264; i += 512) ((bf16*)hs[0])[i] = (bf16)0.f;
  __syncthreads();

  for (int t = 0; t < cS; ++t) {
    const int buf = t & 1, nbuf = buf ^ 1;
    prefetch(t + 1);

    bf16x8 av[8];
#pragma unroll
    for (int kf = 0; kf < 8; ++kf)
      av[kf] = *(const bf16x8*)(&hs[buf][lr][kf * 32 + lh * 8]);

    float gir[2][4], giz[2][4], gin[2][4];
#pragma unroll
    for (int ut = 0; ut < 2; ++ut) {
      const int u = u0 + ut * 16 + lr;
#pragma unroll
      for (int r = 0; r < 4; ++r) {
        const int b = lh * 4 + r;
        gir[ut][r] = gilds[buf][b][u];
        giz[ut][r] = gilds[buf][b][256 + u];
        gin[ut][r] = gilds[buf][b][512 + u];
      }
    }

    f32x4 acc[6];
#pragma unroll
    for (int j = 0; j < 6; ++j)
#pragma unroll
      for (int r = 0; r < 4; ++r) acc[j][r] = 0.f;

#pragma unroll
    for (int kf = 0; kf < 8; ++kf)
#pragma unroll
      for (int nt = 0; nt < 6; ++nt)
        acc[nt] = __builtin_amdgcn_mfma_f32_16x16x32_bf16(av[kf], Bf[nt][kf], acc[nt], 0, 0, 0);

#pragma unroll
    for (int ut = 0; ut < 2; ++ut) {
      const int u = u0 + ut * 16 + lr;
#pragma unroll
      for (int r = 0; r < 4; ++r) {
        const int b = lh * 4 + r;
        float rr = sigm(gir[ut][r] + acc[ut][r] + bh[ut]);
        float zz = sigm(giz[ut][r] + acc[2 + ut][r] + bh[2 + ut]);
        float nn = tanh_f(gin[ut][r] + rr * (acc[4 + ut][r] + bh[4 + ut]));
        float hnew = (1.f - zz) * nn + zz * hreg[ut][r];
        hreg[ut][r] = hnew;
        hs[nbuf][b][u] = (bf16)hnew;
      }
    }

    __syncthreads();

    {
      const int s_src = dir ? (cS - 1 - t) : t;
      const int row = tid >> 5, c8 = tid & 31;
      bf16x8 v = *(const bf16x8*)(&hs[nbuf][row][c8 * 8]);
      *(bf16x8*)(states + ((size_t)s_src * cB + bc * 16 + row) * cH + dir * 256 + c8 * 8) = v;
    }
  }

#pragma unroll
  for (int ut = 0; ut < 2; ++ut)
#pragma unroll
    for (int r = 0; r < 4; ++r)
      hfin[((size_t)dir * cB + bc * 16 + lh * 4 + r) * cH2 + u0 + ut * 16 + lr] = hreg[ut][r];
}

// ---------------- decoder: attention (64 blocks, one per batch row) ----------------
__global__ __launch_bounds__(256) void attn_k(
    const bf16* __restrict__ hin, const float* __restrict__ Wd, const float* __restrict__ bd,
    const float* __restrict__ Wo, const float* __restrict__ bo,
    const float* __restrict__ epT, const bf16* __restrict__ sgT,
    const float* __restrict__ emb, const int* __restrict__ trg, int t,
    bf16* __restrict__ xh) {
  const int b = blockIdx.x, tid = threadIdx.x;
  const int lane = tid & 63, wid = tid >> 6;
  __shared__ float hsh[512];
  __shared__ float dsh[100];
  __shared__ float esh[400];
  __shared__ float red[16];

  for (int k = tid; k < 512; k += 256) hsh[k] = (float)hin[b * 512 + k];
  __syncthreads();

  for (int jj = 0; jj < 25; ++jj) {
    const int j = wid * 25 + jj;
    const float* wr = Wd + (size_t)j * 512 + lane * 8;
    float a = 0.f;
#pragma unroll
    for (int q = 0; q < 8; ++q) a += wr[q] * hsh[lane * 8 + q];
#pragma unroll
    for (int m = 1; m < 64; m <<= 1) a += __shfl_xor(a, m);
    if (lane == 0) dsh[j] = a + bd[j];
  }
  __syncthreads();

  const float bo0 = bo[0];
  const float* ep0 = epT + (size_t)b * cM * cS;
  float e0, e1 = -3.4e38f;
  {
    const float* p = ep0 + tid;
    float a = bo0;
#pragma unroll 4
    for (int j = 0; j < 100; ++j) a += Wo[j] * tanh_f(dsh[j] + p[j * cS]);
    e0 = a;
  }
  if (tid < 144) {
    const float* p = ep0 + 256 + tid;
    float a = bo0;
#pragma unroll 4
    for (int j = 0; j < 100; ++j) a += Wo[j] * tanh_f(dsh[j] + p[j * cS]);
    e1 = a;
  }
  float mx = fmaxf(e0, e1);
#pragma unroll
  for (int msk = 1; msk < 64; msk <<= 1) mx = fmaxf(mx, __shfl_xor(mx, msk));
  if (lane == 0) red[wid] = mx;
  __syncthreads();
  mx = fmaxf(fmaxf(red[0], red[1]), fmaxf(red[2], red[3]));

  float a0 = __expf(e0 - mx);
  float a1 = (tid < 144) ? __expf(e1 - mx) : 0.f;
  esh[tid] = a0;
  if (tid < 144) esh[tid + 256] = a1;
  float sm = a0 + a1;
#pragma unroll
  for (int msk = 1; msk < 64; msk <<= 1) sm += __shfl_xor(sm, msk);
  if (lane == 0) red[8 + wid] = sm;
  __syncthreads();
  const float inv = 1.f / (red[8] + red[9] + red[10] + red[11]);

  {
    const bf16* sp0 = sgT + ((size_t)b * cH + tid) * cS;
    const bf16* sp1 = sp0 + (size_t)256 * cS;
    float c0 = 0.f, c1 = 0.f;
    for (int s = 0; s < cS; s += 8) {
      bf16x8 v0 = *(const bf16x8*)(sp0 + s);
      bf16x8 v1 = *(const bf16x8*)(sp1 + s);
#pragma unroll
      for (int j = 0; j < 8; ++j) {
        float wj = esh[s + j];
        c0 += wj * (float)v0[j];
        c1 += wj * (float)v1[j];
      }
    }
    xh[(size_t)b * cKcat + tid] = (bf16)(c0 * inv);
    xh[(size_t)b * cKcat + 256 + tid] = (bf16)(c1 * inv);
  }
  const int tok = trg[b * cT + t];
  xh[(size_t)b * cKcat + 512 + tid] = (bf16)emb[(size_t)tok * cE + tid];
  for (int k = tid; k < 512; k += 256) xh[(size_t)b * cKcat + 768 + k] = hin[b * 512 + k];
}

// ---------------- decoder: fused GRU cell (8 blocks), swizzled Wp ----------------
__global__ __launch_bounds__(256) void gru_k(
    const bf16* __restrict__ xh, const bf16* __restrict__ Wp, const float* __restrict__ bp,
    const float* __restrict__ hin_f, float* __restrict__ hout_f, bf16* __restrict__ hallt) {
  const int tid = threadIdx.x;
  const int lane = tid & 63, wid = tid >> 6;
  const int w = blockIdx.x * 4 + wid;
  const int n0 = w << 6, lr = lane & 15, lh = lane >> 4;
  f32x4 acc[4][4];
#pragma unroll
  for (int i = 0; i < 4; ++i)
#pragma unroll
    for (int j = 0; j < 4; ++j)
#pragma unroll
      for (int r = 0; r < 4; ++r) acc[i][j][r] = 0.f;
#pragma unroll 2
  for (int k0 = 0; k0 < cKcat; k0 += 32) {
    bf16x8 av[4], bw[4];
#pragma unroll
    for (int mt = 0; mt < 4; ++mt)
      av[mt] = *(const bf16x8*)(xh + (size_t)(mt * 16 + lr) * cKcat + k0 + lh * 8);
#pragma unroll
    for (int nt = 0; nt < 4; ++nt)
      bw[nt] = *(const bf16x8*)(Wp + (((size_t)(w * 4 + nt) * 40 + (k0 >> 5)) * 64 + lr * 4 + lh) * 8);
#pragma unroll
    for (int mt = 0; mt < 4; ++mt)
#pragma unroll
      for (int nt = 0; nt < 4; ++nt)
        acc[mt][nt] = __builtin_amdgcn_mfma_f32_16x16x32_bf16(av[mt], bw[nt], acc[mt][nt], 0, 0, 0);
  }
  const int u = (n0 >> 2) + lr;
  const float br = bp[n0 + lr];
  const float bz2 = bp[n0 + 16 + lr];
  const float bi2 = bp[n0 + 32 + lr];
  const float bh2 = bp[n0 + 48 + lr];
#pragma unroll
  for (int mt = 0; mt < 4; ++mt)
#pragma unroll
    for (int r = 0; r < 4; ++r) {
      const int bb = mt * 16 + lh * 4 + r;
      float rr = sigm(acc[mt][0][r] + br);
      float zz = sigm(acc[mt][1][r] + bz2);
      float nn = tanh_f(acc[mt][2][r] + bi2 + rr * (acc[mt][3][r] + bh2));
      float h2v = (1.f - zz) * nn + zz * hin_f[(size_t)bb * cH + u];
      hout_f[(size_t)bb * cH + u] = h2v;
      hallt[(size_t)bb * cH + u] = (bf16)h2v;
    }
}

// ---------------- ONE big logits GEMM over all 24 steps: M=1536, N=50000, K=512 ----------------
// A = hall (row-major), B = WvS (fragment-swizzled) -> per-row-tile (max,sumexp) partials
__global__ __launch_bounds__(256) void biglogits_k(
    const bf16* __restrict__ hall, const bf16* __restrict__ WvS,
    const float* __restrict__ bv, float* __restrict__ partials) {
  const int tid = threadIdx.x;
  const int lane = tid & 63, wid = tid >> 6;
  const int im = blockIdx.x % cTD;          // 24 M-tiles
  const int in = (blockIdx.x / cTD) * 4 + wid;  // up to 782 N-tiles
  if (in >= cNTV) return;
  const int m0 = im << 6, lr = lane & 15, lh = lane >> 4;

  f32x4 acc[4][4];
#pragma unroll
  for (int i = 0; i < 4; ++i)
#pragma unroll
    for (int j = 0; j < 4; ++j)
#pragma unroll
      for (int r = 0; r < 4; ++r) acc[i][j][r] = 0.f;
  bf16x8 bz;
#pragma unroll
  for (int q = 0; q < 8; ++q) bz[q] = (bf16)0.f;

#pragma unroll 2
  for (int k0 = 0; k0 < cH; k0 += 32) {
    bf16x8 av[4], bw[4];
#pragma unroll
    for (int mt = 0; mt < 4; ++mt)
      av[mt] = *(const bf16x8*)(hall + (size_t)(m0 + mt * 16 + lr) * cH + k0 + lh * 8);
#pragma unroll
    for (int nt = 0; nt < 4; ++nt) {
      const int tile = in * 4 + nt;
      bw[nt] = (tile < cVT)
                   ? *(const bf16x8*)(WvS + (((size_t)tile * 16 + (k0 >> 5)) * 64 + lr * 4 + lh) * 8)
                   : bz;
    }
#pragma unroll
    for (int mt = 0; mt < 4; ++mt)
#pragma unroll
      for (int nt = 0; nt < 4; ++nt)
        acc[mt][nt] = __builtin_amdgcn_mfma_f32_16x16x32_bf16(av[mt], bw[nt], acc[mt][nt], 0, 0, 0);
  }

#pragma unroll
  for (int mt = 0; mt < 4; ++mt) {
#pragma unroll
    for (int r = 0; r < 4; ++r) {
      const int m = m0 + mt * 16 + lh * 4 + r;
      float vv[4];
      float mx = -3.4e38f;
#pragma unroll
      for (int nt = 0; nt < 4; ++nt) {
        int n = (in << 6) + nt * 16 + lr;
        float v = (n < cV) ? (acc[mt][nt][r] + bv[n]) : -3.4e38f;
        vv[nt] = v;
        mx = fmaxf(mx, v);
      }
#pragma unroll
      for (int msk = 1; msk < 16; msk <<= 1) mx = fmaxf(mx, __shfl_xor(mx, msk));
      float sm = 0.f;
#pragma unroll
      for (int nt = 0; nt < 4; ++nt) {
        int n = (in << 6) + nt * 16 + lr;
        if (n < cV) sm += __expf(vv[nt] - mx);
      }
#pragma unroll
      for (int msk = 1; msk < 16; msk <<= 1) sm += __shfl_xor(sm, msk);
      if (lr == 0) {
        float* p = partials + ((size_t)m * cNTV + in) * 2;
        p[0] = mx;
        p[1] = sm;
      }
    }
  }
}

// ---------------- per-(step,row) loss: 1536 blocks x 1 wave ----------------
__global__ __launch_bounds__(64) void rowloss_all_k(
    const float* __restrict__ partials, const bf16* __restrict__ hall,
    const float* __restrict__ Wv, const float* __restrict__ bv,
    const int* __restrict__ trg, float* __restrict__ rnll, float* __restrict__ rw) {
  const int m = blockIdx.x, tid = threadIdx.x;
  const int t = m >> 6, bb = m & 63;
  float mx = -3.4e38f, sm = 0.f;
  const float* pr = partials + (size_t)m * cNTV * 2;
  for (int p = tid; p < cNTV; p += 64) {
    float m2 = pr[p * 2], s2 = pr[p * 2 + 1];
    if (m2 > mx) { sm = sm * __expf(mx - m2) + s2; mx = m2; }
    else sm += s2 * __expf(m2 - mx);
  }
#pragma unroll
  for (int msk = 1; msk < 64; msk <<= 1) {
    float om = __shfl_xor(mx, msk), os = __shfl_xor(sm, msk);
    if (om > mx) { sm = sm * __expf(mx - om) + os; mx = om; }
    else sm += os * __expf(om - mx);
  }
  const int tok = trg[bb * cT + t];
  float dot = 0.f;
  {
    const float* wr = Wv + (size_t)tok * cH + tid * 8;
    const bf16* hr = hall + (size_t)m * cH + tid * 8;
    bf16x8 h8 = *(const bf16x8*)hr;
#pragma unroll
    for (int j = 0; j < 8; ++j) dot += (float)h8[j] * wr[j];
  }
#pragma unroll
  for (int msk = 1; msk < 64; msk <<= 1) dot += __shfl_xor(dot, msk);
  if (tid == 0) {
    float lse = mx + __logf(sm);
    float nll = lse - (dot + bv[tok]);
    float wgt = (tok != cEOS) ? 1.f : 0.f;
    rnll[m] = wgt * nll;
    rw[m] = wgt;
  }
}

__global__ __launch_bounds__(64) void final_loss_k(const float* __restrict__ rnll,
                                                   const float* __restrict__ rw,
                                                   float* __restrict__ out) {
  __shared__ float sl[32];
  const int t = threadIdx.x;
  if (t < cTD) {
    float a = 0.f, d = 0.f;
    for (int b = 0; b < cB; ++b) { a += rnll[t * cB + b]; d += rw[t * cB + b]; }
    sl[t] = a / d;
  }
  __syncthreads();
  if (t == 0) {
    float s = 0.f;
    for (int i = 0; i < cTD; ++i) s += sl[i];
    out[0] = s / (float)cB;
  }
}

// ---------------- host ----------------
extern "C" void kernel_launch(void* const* d_in, const int* in_sizes, int n_in,
                              void* d_out, int out_size, void* d_ws, size_t ws_size,
                              hipStream_t stream) {
  (void)in_sizes; (void)n_in; (void)out_size; (void)ws_size;
  const int* src = (const int*)d_in[0];
  const int* trg = (const int*)d_in[1];
  const float* emb = (const float*)d_in[2];
  const float* Wih_f = (const float*)d_in[3];
  const float* Whh_f = (const float*)d_in[4];
  const float* bih_f = (const float*)d_in[5];
  const float* bhh_f = (const float*)d_in[6];
  const float* Wih_b = (const float*)d_in[7];
  const float* Whh_b = (const float*)d_in[8];
  const float* bih_b = (const float*)d_in[9];
  const float* bhh_b = (const float*)d_in[10];
  const float* W1 = (const float*)d_in[11];
  const float* b1 = (const float*)d_in[12];
  const float* W2 = (const float*)d_in[13];
  const float* b2 = (const float*)d_in[14];
  const float* Wd = (const float*)d_in[15];
  const float* bd = (const float*)d_in[16];
  const float* We = (const float*)d_in[17];
  const float* be = (const float*)d_in[18];
  const float* Wo = (const float*)d_in[19];
  const float* bo = (const float*)d_in[20];
  const float* Wih_c = (const float*)d_in[21];
  const float* Whh_c = (const float*)d_in[22];
  const float* bih_c = (const float*)d_in[23];
  const float* bhh_c = (const float*)d_in[24];
  const float* Wv = (const float*)d_in[25];
  const float* bv = (const float*)d_in[26];
  float* out = (float*)d_out;

  char* ws = (char*)d_ws;
  size_t off = 0;
  auto carve = [&](size_t bytes) -> void* {
    void* p = ws + off;
    off += (bytes + 255) & ~(size_t)255;
    return p;
  };
  bf16* wcat = (bf16*)carve(TOT_W * 2);
  bf16* WvS = wcat + OFF_WV;
  bf16* Wihf_b = wcat + OFF_WIHF;
  bf16* Whhf_b = wcat + OFF_WHHF;
  bf16* Wihb_b = wcat + OFF_WIHB;
  bf16* Whhb_b = wcat + OFF_WHHB;
  bf16* W1_b = wcat + OFF_W1;
  bf16* W2_b = wcat + OFF_W2;
  bf16* We_b = wcat + OFF_WE;
  bf16* Wp_b = (bf16*)carve((size_t)cN4 * cKcat * 2);
  float* bp = (float*)carve((size_t)cN4 * 4);
  bf16* embeds = (bf16*)carve((size_t)cSB * cE * 2);
  float* gi_f = (float*)carve((size_t)cSB * cG2 * 4);
  float* gi_b = (float*)carve((size_t)cSB * cG2 * 4);
  bf16* states = (bf16*)carve((size_t)cSB * cH * 2);
  bf16* statesg = (bf16*)carve((size_t)cSB * cH * 2);
  bf16* statesgT = (bf16*)carve((size_t)cSB * cH * 2);
  float* hfin = (float*)carve((size_t)2 * cB * cH2 * 4);
  bf16* hdec0_bf = (bf16*)carve((size_t)cB * cH * 2);
  float* hdec0_f = (float*)carve((size_t)cB * cH * 4);
  float* hf0 = (float*)carve((size_t)cB * cH * 4);
  float* hf1 = (float*)carve((size_t)cB * cH * 4);
  float* hw2 = (float*)carve((size_t)cB * cH * 4);
  float* epT = (float*)carve((size_t)cB * cM * cS * 4);
  bf16* xh = (bf16*)carve((size_t)cB * cKcat * 2);
  bf16* hall = (bf16*)carve((size_t)cTD * cB * cH * 2);
  float* partials = (float*)carve((size_t)cTD * cB * cNTV * 2 * 4);
  float* rnll = (float*)carve((size_t)cTD * cB * 4);
  float* rw = (float*)carve((size_t)cTD * cB * 4);

  auto gemm0 = [&](const bf16* A, const bf16* Bm, const float* bias, float* outF,
                   int M, int N, int K, int ldo) {
    GArgs ga{A, Bm, bias, outF, nullptr, nullptr, nullptr, M, N, K, ldo};
    int waves = (M / 64) * ((N + 63) / 64);
    gemm64_k<0><<<dim3((waves + 3) / 4), dim3(256), 0, stream>>>(ga);
  };

  // weight prep
  cvt8_k<<<dim3((TOT_W / 4 + 255) / 256), dim3(256), 0, stream>>>(
      Wv, Wih_f, Whh_f, Wih_b, Whh_b, W1, W2, We, wcat);
  build_wp_k<<<dim3((cN4 * cKcat + 255) / 256), dim3(256), 0, stream>>>(
      Wih_c, Whh_c, bih_c, bhh_c, Wp_b, bp);

  // encoder
  gather_k<<<dim3(cSB * cE / 256), dim3(256), 0, stream>>>(src, emb, embeds);
  gemm0(embeds, Wihf_b, bih_f, gi_f, cSB, cG2, cE, cG2);
  gemm0(embeds, Wihb_b, bih_b, gi_b, cSB, cG2, cE, cG2);
  enc_rnn_k<<<dim3(8), dim3(512), 0, stream>>>(Whhf_b, Whhb_b, gi_f, gi_b, bhh_f, bhh_b,
                                               hfin, states);
  concat_k<<<dim3((cB * cH + 255) / 256), dim3(256), 0, stream>>>(
      hfin, hfin + (size_t)cB * cH2, hdec0_bf, hdec0_f);
  gemm0(hdec0_bf, W2_b, b2, hw2, cB, cH, cH, cH);
  {  // sgate: statesg = sigmoid(states@W1^T + b1 + hw2) * states
    GArgs ga{states, W1_b, b1, nullptr, statesg, hw2, states, cSB, cH, cH, cH};
    int waves = (cSB / 64) * (cH / 64);
    gemm64_k<1><<<dim3((waves + 3) / 4), dim3(256), 0, stream>>>(ga);
  }
  {  // encproj, transposed: epT[b][j][s]
    GArgs ga{statesg, We_b, be, epT, nullptr, nullptr, nullptr, cSB, cM, cH, 0};
    int waves = (cSB / 64) * ((cM + 63) / 64);
    gemm64_k<4><<<dim3((waves + 3) / 4), dim3(256), 0, stream>>>(ga);
  }
  transp_k<<<dim3(cB), dim3(256), 0, stream>>>(statesg, statesgT);

  // decoder h-chain: logits deferred out of the loop
  for (int t = 0; t < cTD; ++t) {
    const bf16* hin_bf = (t == 0) ? hdec0_bf : (hall + (size_t)(t - 1) * cB * cH);
    const float* hin_f = (t == 0) ? hdec0_f : ((t & 1) ? hf0 : hf1);
    float* hout_f = (t & 1) ? hf1 : hf0;

    attn_k<<<dim3(cB), dim3(256), 0, stream>>>(hin_bf, Wd, bd, Wo, bo, epT, statesgT,
                                               emb, trg, t, xh);
    gru_k<<<dim3(8), dim3(256), 0, stream>>>(xh, Wp_b, bp, hin_f, hout_f,
                                             hall + (size_t)t * cB * cH);
  }

  // all-steps logits + loss
  biglogits_k<<<dim3(cTD * ((cNTV + 3) / 4)), dim3(256), 0, stream>>>(hall, WvS, bv, partials);
  rowloss_all_k<<<dim3(cTD * cB), dim3(64), 0, stream>>>(partials, hall, Wv, bv, trg, rnll, rw);
  final_loss_k<<<dim3(1), dim3(64), 0, stream>>>(rnll, rw, out);
}